// Round 3
// baseline (1078.747 us; speedup 1.0000x reference)
//
#include <hip/hip_runtime.h>
#include <cstdint>
#include <cstddef>

// ---------------------------------------------------------------------------
// EarthSpecificBlock (Pangu-style 3D window attention block) for MI355X.
// B=2, L=57600 (8x60x120), C=256, H=8, hd=32, WIN=(2,6,12) -> N=144,
// nW=40 window types, B_=20, HID=1024.
// QKV kept in WINDOW-ORDERED layout (wrow = (b_*40+w)*144 + n) so attention
// addressing is fully linear; row permutation applied in GEMM epilogues.
// ---------------------------------------------------------------------------

typedef __attribute__((ext_vector_type(8))) short bf16x8;
typedef __attribute__((ext_vector_type(4))) float f32x4;
typedef unsigned short ushort_t;

#define MFMA16(a, b, c) __builtin_amdgcn_mfma_f32_16x16x32_bf16(a, b, c, 0, 0, 0)

__device__ __forceinline__ unsigned short f2bf(float f) {
  union { float f; unsigned u; } c; c.f = f;
  unsigned r = c.u + 0x7FFFu + ((c.u >> 16) & 1u);   // RNE
  return (unsigned short)(r >> 16);
}

__device__ __forceinline__ void gload16(const void* g, void* l) {
  __builtin_amdgcn_global_load_lds(
      (const __attribute__((address_space(1))) unsigned int*)g,
      (__attribute__((address_space(3))) unsigned int*)(uintptr_t)l,
      16, 0, 0);
}

// ---------------------------------------------------------------------------
// fused f32 -> bf16 weight convert (qkv|proj|fc1|fc2 packed in one buffer)
// ---------------------------------------------------------------------------
__global__ void cvt_all(const float* __restrict__ a, const float* __restrict__ b,
                        const float* __restrict__ c, const float* __restrict__ d,
                        ushort_t* __restrict__ out) {
  const int i = blockIdx.x * 256 + threadIdx.x;   // 786432 exact
  float v;
  if (i < 196608) v = a[i];
  else if (i < 262144) v = b[i - 196608];
  else if (i < 524288) v = c[i - 262144];
  else v = d[i - 524288];
  out[i] = f2bf(v);
}

// ---------------------------------------------------------------------------
// permutation maps: wrow = (b_*40+w)*144+n  <->  nat = b*57600 + p*7200+lat*120+lon
// ---------------------------------------------------------------------------
__global__ void make_perm(int* __restrict__ w2n, int* __restrict__ n2w) {
  const int wr = blockIdx.x * 256 + threadIdx.x;   // 115200 exact
  const int n = wr % 144, w = (wr / 144) % 40, b_ = wr / 5760;
  const int b = b_ / 10, ln = b_ % 10, pi = w / 10, li = w % 10;
  const int wp = n / 72, rem = n % 72, wl = rem / 12, ww = rem % 12;
  const int nat = b * 57600 + ((pi * 2 + wp) * 60 + li * 6 + wl) * 120 + ln * 12 + ww;
  w2n[wr] = nat;
  n2w[nat] = wr;
}

// ---------------------------------------------------------------------------
// Earth position bias gather: out[((h*40+w)*144+n)*144+m] = tbl[idx][w][h]
// ---------------------------------------------------------------------------
__global__ void bias_gather(const float* __restrict__ tbl, float* __restrict__ out) {
  const int t = blockIdx.x * 256 + threadIdx.x;   // 6,635,520 exact
  const int m = t % 144;
  const int n = (t / 144) % 144;
  const int wh = t / 20736;
  const int w = wh % 40, h = wh / 40;
  const int zq = n / 72, hq = (n / 12) % 6, wq = n % 12;
  const int zk = m / 72, hk = (m / 12) % 6, wk = m % 12;
  const int idx = (zq + 2 * zk) * 828 + (hq + 6 * hk) * 23 + (wq - wk + 11);
  out[t] = tbl[idx * 320 + w * 8 + h];
}

// ---------------------------------------------------------------------------
// LayerNorm over C=256, one wave per token, fp32 in -> bf16 out
// ---------------------------------------------------------------------------
__global__ __launch_bounds__(256) void ln_kernel(
    const float* __restrict__ in, const float* __restrict__ g,
    const float* __restrict__ b, ushort_t* __restrict__ out) {
  const int wid = threadIdx.x >> 6, lane = threadIdx.x & 63;
  const size_t tok = (size_t)blockIdx.x * 4 + wid;
  const float4 v = *(const float4*)(in + tok * 256 + lane * 4);
  float s  = v.x + v.y + v.z + v.w;
  float sq = v.x * v.x + v.y * v.y + v.z * v.z + v.w * v.w;
#pragma unroll
  for (int off = 1; off < 64; off <<= 1) {
    s  += __shfl_xor(s, off);
    sq += __shfl_xor(sq, off);
  }
  const float mu = s * (1.0f / 256.0f);
  const float rs = rsqrtf(sq * (1.0f / 256.0f) - mu * mu + 1e-5f);
  const float4 gg = *(const float4*)(g + lane * 4);
  const float4 bb = *(const float4*)(b + lane * 4);
  ushort4 st;
  st.x = f2bf((v.x - mu) * rs * gg.x + bb.x);
  st.y = f2bf((v.y - mu) * rs * gg.y + bb.y);
  st.z = f2bf((v.z - mu) * rs * gg.z + bb.z);
  st.w = f2bf((v.w - mu) * rs * gg.w + bb.w);
  *(ushort4*)(out + tok * 256 + lane * 4) = st;
}

// ---------------------------------------------------------------------------
// bf16 MFMA GEMM: C[M][N] = A[M][K] * Bw[N][K]^T, 128x128 tile, BK=64,
// 4 waves (each 64x64), global_load_lds + XOR swizzle, XCD-chunked blockIdx
// swizzle (grid must be divisible by 8; consecutive tileN blocks -> same XCD).
// EPI: 0=qkv(bias+qscale,bf16,out rows permuted by perm=n2w)
//      1=proj(bias+res,f32,out rows permuted by perm=w2n; res natural)
//      2=fc1(bias+gelu,bf16)  3=fc2(bias+res,f32)
// ---------------------------------------------------------------------------
template <int EPI>
__global__ __launch_bounds__(256) void gemm_kernel(
    const ushort_t* __restrict__ A, const ushort_t* __restrict__ Bw,
    const float* __restrict__ bias, const float* __restrict__ res,
    const int* __restrict__ perm, void* __restrict__ outp,
    int M, int N, int K) {
  __shared__ unsigned char lds[32768];
  unsigned char* ldsA = lds;
  unsigned char* ldsB = lds + 16384;
  const int tid = threadIdx.x;
  const int lane = tid & 63, wid = tid >> 6;
  const int ntn = N >> 7;
  const int cpx = (int)gridDim.x >> 3;
  const int orig = ((int)blockIdx.x & 7) * cpx + ((int)blockIdx.x >> 3);
  const int tileM = (orig / ntn) << 7;
  const int tileN = (orig % ntn) << 7;
  const unsigned baseoff = ((unsigned)wid << 10) | ((unsigned)lane << 4);

  f32x4 acc[4][4];
#pragma unroll
  for (int i = 0; i < 4; i++)
#pragma unroll
    for (int j = 0; j < 4; j++) acc[i][j] = (f32x4){0.f, 0.f, 0.f, 0.f};

  const int wm = (wid >> 1) << 6;
  const int wn = (wid & 1) << 6;

  for (int k0 = 0; k0 < K; k0 += 64) {
#pragma unroll
    for (int i = 0; i < 4; i++) {
      const unsigned o = baseoff + (unsigned)i * 4096u;
      const unsigned row = o >> 7, cb = o & 127u;
      const unsigned scb = cb ^ ((row & 7u) << 4);
      gload16(A + (size_t)(tileM + row) * K + k0 + (scb >> 1),
              ldsA + (i << 12) + (wid << 10));
      gload16(Bw + (size_t)(tileN + row) * K + k0 + (scb >> 1),
              ldsB + (i << 12) + (wid << 10));
    }
    asm volatile("s_waitcnt vmcnt(0)" ::: "memory");
    __syncthreads();
#pragma unroll
    for (int ks = 0; ks < 2; ks++) {
      bf16x8 af[4], bf[4];
#pragma unroll
      for (int mi = 0; mi < 4; mi++) {
        const int row = wm + mi * 16 + (lane & 15);
        const unsigned cb = ((unsigned)(ks * 64) + (((unsigned)lane >> 4) << 4)) ^ ((row & 7) << 4);
        af[mi] = *(const bf16x8*)(ldsA + row * 128 + cb);
      }
#pragma unroll
      for (int ni = 0; ni < 4; ni++) {
        const int row = wn + ni * 16 + (lane & 15);
        const unsigned cb = ((unsigned)(ks * 64) + (((unsigned)lane >> 4) << 4)) ^ ((row & 7) << 4);
        bf[ni] = *(const bf16x8*)(ldsB + row * 128 + cb);
      }
#pragma unroll
      for (int mi = 0; mi < 4; mi++)
#pragma unroll
        for (int ni = 0; ni < 4; ni++)
          acc[mi][ni] = MFMA16(af[mi], bf[ni], acc[mi][ni]);
    }
    __syncthreads();
  }

  const int cr = ((lane >> 4) << 2);
  const int cc = lane & 15;
#pragma unroll
  for (int mi = 0; mi < 4; mi++) {
    int srow[4];
#pragma unroll
    for (int r = 0; r < 4; r++) {
      const int rowg = tileM + wm + mi * 16 + cr + r;
      srow[r] = (EPI <= 1) ? perm[rowg] : rowg;
    }
#pragma unroll
    for (int ni = 0; ni < 4; ni++) {
      const int colg = tileN + wn + ni * 16 + cc;
      const float bv = bias[colg];
#pragma unroll
      for (int r = 0; r < 4; r++) {
        const size_t oidx = (size_t)srow[r] * N + colg;
        float v = acc[mi][ni][r] + bv;
        if (EPI == 0) {
          if (colg < 256) v *= 0.17677669529663687f;
          ((ushort_t*)outp)[oidx] = f2bf(v);
        } else if (EPI == 1) {
          ((float*)outp)[oidx] = v + res[oidx];
        } else if (EPI == 2) {
          const float ge = 0.5f * v * (1.0f + erff(v * 0.7071067811865475f));
          ((ushort_t*)outp)[oidx] = f2bf(ge);
        } else {
          ((float*)outp)[oidx] = v + res[oidx];
        }
      }
    }
  }
}

// ---------------------------------------------------------------------------
// Window attention v3: qkv window-ordered -> fully linear addressing.
// 3 waves/block, wave handles fr = wid*3..wid*3+2 (balanced 3/3/3).
// S in registers, wave-parallel softmax, bias streamed from precomputed
// [h][w][144][144] (L3-resident). PV as O^T (A=V^T rows-of-e, B=P rows-of-n)
// for contiguous 8B output stores. XCD-chunked swizzle: 8 heads of one
// window land on one XCD (share QKV in L2).
// ---------------------------------------------------------------------------
__global__ __launch_bounds__(192, 4) void attn_kernel(
    const ushort_t* __restrict__ qkv,      // [115200][768] window-ordered
    const float* __restrict__ biasArr,     // [(h*40+w)*144+n][144]
    ushort_t* __restrict__ outp) {         // [115200][256] window-ordered
  __shared__ ushort_t Vt[32 * 184];        // V^T rows e, cols m (pad->0)
  __shared__ ushort_t Pw[3][16 * 184];     // per-wave P rows n-local, cols m

  const int bi = blockIdx.x;
  const int orig = (bi & 7) * 800 + (bi >> 3);
  const int h  = orig & 7;
  const int wg = orig >> 3;                // b_*40 + w
  const int w  = wg % 40;
  const int tid = threadIdx.x, lane = tid & 63, wid = tid / 64;
  const int lr = lane & 15, hi = lane >> 4;
  const size_t wbase = (size_t)wg * 144;
  const ushort_t* qbase = qkv + wbase * 768 + h * 32;

  // stage V^T (coalesced 64B reads per token; scattered 2B LDS writes)
  for (int idx = tid; idx < 4608; idx += 192) {
    const int n = idx >> 5, e = idx & 31;
    Vt[e * 184 + n] = qbase[(size_t)n * 768 + 512 + e];
  }
  for (int idx = tid; idx < 512; idx += 192)   // zero pad keys 144..159
    Vt[(idx >> 4) * 184 + 144 + (idx & 15)] = 0;
  {
    ushort_t* pw = Pw[wid];                    // zero P pad cols once
#pragma unroll
    for (int r = 0; r < 4; r++) pw[(hi * 4 + r) * 184 + 144 + lr] = 0;
  }
  __syncthreads();

  const float* bb0 = biasArr + (size_t)(h * 40 + w) * 20736;
  ushort_t* pw = Pw[wid];

  for (int it = 0; it < 3; it++) {
    const int fr = wid * 3 + it;               // 0..8
    const bf16x8 qf = *(const bf16x8*)(qbase + (size_t)(fr * 16 + lr) * 768 + hi * 8);

    f32x4 s[9];
#pragma unroll
    for (int fc = 0; fc < 9; fc++) {
      const bf16x8 kf = *(const bf16x8*)(qbase + (size_t)(fc * 16 + lr) * 768 + 256 + hi * 8);
      f32x4 z = (f32x4){0.f, 0.f, 0.f, 0.f};
      s[fc] = MFMA16(qf, kf, z);
    }

    // + bias (coalesced: 16 lanes consecutive m)
    const float* brow = bb0 + (size_t)(fr * 16 + hi * 4) * 144 + lr;
#pragma unroll
    for (int fc = 0; fc < 9; fc++)
#pragma unroll
      for (int r = 0; r < 4; r++)
        s[fc][r] += brow[(size_t)r * 144 + fc * 16];

    // wave-parallel softmax (rows n = fr*16+hi*4+r; cols over fc regs + lr)
    float mx[4], sm[4];
#pragma unroll
    for (int r = 0; r < 4; r++) mx[r] = -1e30f;
#pragma unroll
    for (int fc = 0; fc < 9; fc++)
#pragma unroll
      for (int r = 0; r < 4; r++) mx[r] = fmaxf(mx[r], s[fc][r]);
#pragma unroll
    for (int off = 1; off < 16; off <<= 1)
#pragma unroll
      for (int r = 0; r < 4; r++) mx[r] = fmaxf(mx[r], __shfl_xor(mx[r], off));
#pragma unroll
    for (int r = 0; r < 4; r++) sm[r] = 0.f;
#pragma unroll
    for (int fc = 0; fc < 9; fc++)
#pragma unroll
      for (int r = 0; r < 4; r++) {
        s[fc][r] = __expf(s[fc][r] - mx[r]);
        sm[r] += s[fc][r];
      }
#pragma unroll
    for (int off = 1; off < 16; off <<= 1)
#pragma unroll
      for (int r = 0; r < 4; r++) sm[r] += __shfl_xor(sm[r], off);
    float inv[4];
#pragma unroll
    for (int r = 0; r < 4; r++) inv[r] = 1.0f / sm[r];

    // P -> per-wave LDS tile (rows n-local, cols m)
#pragma unroll
    for (int fc = 0; fc < 9; fc++)
#pragma unroll
      for (int r = 0; r < 4; r++)
        pw[(hi * 4 + r) * 184 + fc * 16 + lr] = f2bf(s[fc][r] * inv[r]);

    // PV as O^T: D row = e (A=V^T), col = n-local (B=P rows)
#pragma unroll
    for (int eblk = 0; eblk < 2; eblk++) {
      f32x4 acc = (f32x4){0.f, 0.f, 0.f, 0.f};
#pragma unroll
      for (int kb = 0; kb < 5; kb++) {
        const bf16x8 a  = *(const bf16x8*)(Vt + (eblk * 16 + lr) * 184 + kb * 32 + hi * 8);
        const bf16x8 bb = *(const bf16x8*)(pw + lr * 184 + kb * 32 + hi * 8);
        acc = MFMA16(a, bb, acc);
      }
      ushort4 st;
      st.x = f2bf(acc[0]); st.y = f2bf(acc[1]);
      st.z = f2bf(acc[2]); st.w = f2bf(acc[3]);
      *(ushort4*)(outp + (wbase + fr * 16 + lr) * 256 + h * 32 + eblk * 16 + hi * 4) = st;
    }
  }
}

// ---------------------------------------------------------------------------
// launch
// ---------------------------------------------------------------------------
extern "C" void kernel_launch(void* const* d_in, const int* in_sizes, int n_in,
                              void* d_out, int out_size, void* d_ws, size_t ws_size,
                              hipStream_t stream) {
  const float* x      = (const float*)d_in[0];
  const float* n1g    = (const float*)d_in[1];
  const float* n1b    = (const float*)d_in[2];
  const float* qkv_w  = (const float*)d_in[3];
  const float* qkv_b  = (const float*)d_in[4];
  const float* btab   = (const float*)d_in[5];
  const float* proj_w = (const float*)d_in[6];
  const float* proj_b = (const float*)d_in[7];
  const float* n2g    = (const float*)d_in[8];
  const float* n2b    = (const float*)d_in[9];
  const float* fc1_w  = (const float*)d_in[10];
  const float* fc1_b  = (const float*)d_in[11];
  const float* fc2_w  = (const float*)d_in[12];
  const float* fc2_b  = (const float*)d_in[13];
  float* outp = (float*)d_out;

  char* ws = (char*)d_ws;
  // layout (time-disjoint overlaps):
  //  [0, 176.9M)        qkv bf16 [115200][768] window-ordered (later ln2buf 0..59M)
  //  [176.9M, 235.9M)   ln1 out bf16 natural (later: attn out bf16 window-ordered)
  //  [235.9M, 262.5M)   biasA fp32 (attn only; later clobbered by fc1buf)
  //  [262.5M, 263.4M)   n2w, w2n int maps (used before fc1)
  //  [59.0M, 294.9M)    fc1 out bf16 (after attention/proj done)
  //  [294.9M, 296.5M)   bf16 weights
  ushort_t* qkvbuf = (ushort_t*)(ws);
  ushort_t* hbuf   = (ushort_t*)(ws + 176947200);
  float*    biasA  = (float*)(ws + 235929600);
  int*      n2w    = (int*)(ws + 262471680);
  int*      w2n    = (int*)(ws + 262932480);
  ushort_t* ln2buf = (ushort_t*)(ws);
  ushort_t* fc1buf = (ushort_t*)(ws + 58982400);
  ushort_t* wbuf   = (ushort_t*)(ws + 294912000);
  ushort_t* qkvW = wbuf;
  ushort_t* projW = wbuf + 196608;
  ushort_t* fc1W  = wbuf + 262144;
  ushort_t* fc2W  = wbuf + 524288;

  cvt_all<<<3072, 256, 0, stream>>>(qkv_w, proj_w, fc1_w, fc2_w, wbuf);
  make_perm<<<450, 256, 0, stream>>>(w2n, n2w);
  bias_gather<<<25920, 256, 0, stream>>>(btab, biasA);
  ln_kernel<<<28800, 256, 0, stream>>>(x, n1g, n1b, hbuf);

  // QKV (A natural rows; C rows scattered to window order via n2w)
  gemm_kernel<0><<<5400, 256, 0, stream>>>(hbuf, qkvW, qkv_b, nullptr, n2w, qkvbuf, 115200, 768, 256);
  // attention (window-ordered in/out; out -> hbuf)
  attn_kernel<<<6400, 192, 0, stream>>>(qkvbuf, biasA, hbuf);
  // proj + residual(x): A window rows; C rows scattered back via w2n
  gemm_kernel<1><<<1800, 256, 0, stream>>>(hbuf, projW, proj_b, x, w2n, outp, 115200, 256, 256);
  // LN2 on x1 (natural)
  ln_kernel<<<28800, 256, 0, stream>>>(outp, n2g, n2b, ln2buf);
  // FC1 + gelu
  gemm_kernel<2><<<7200, 256, 0, stream>>>(ln2buf, fc1W, fc1_b, nullptr, nullptr, fc1buf, 115200, 1024, 256);
  // FC2 + residual(x1)
  gemm_kernel<3><<<1800, 256, 0, stream>>>(fc1buf, fc2W, fc2_b, outp, nullptr, outp, 115200, 256, 1024);
}